// Round 1
// baseline (33367.044 us; speedup 1.0000x reference)
//
#include <hip/hip_runtime.h>

#define TT 1024
#define BB 256
#define HH 512
#define G4 2048  // 4*H

// ---------------- prep: transposes + bias fuse + state init ----------------
__global__ __launch_bounds__(256) void prep_k(
    const float* __restrict__ Whh, const float* __restrict__ fcW,
    const float* __restrict__ bih, const float* __restrict__ bhh,
    float* __restrict__ WT, float* __restrict__ fcWT, float* __restrict__ bsum,
    float* __restrict__ h0, float* __restrict__ c)
{
    int n  = blockDim.x * gridDim.x;
    int i0 = blockIdx.x * blockDim.x + threadIdx.x;
    // WT[k][r] = Whh[r][k]  (coalesced writes, scattered reads hit L2)
    for (int i = i0; i < HH * G4; i += n) {
        int k = i >> 11, r = i & (G4 - 1);
        WT[i] = Whh[r * HH + k];
    }
    // fcWT[k][t] = fcW[t][k]
    for (int i = i0; i < HH * TT; i += n) {
        int k = i >> 10, t = i & (TT - 1);
        fcWT[i] = fcW[t * HH + k];
    }
    for (int i = i0; i < G4; i += n) bsum[i] = bih[i] + bhh[i];
    for (int i = i0; i < BB * HH; i += n) { h0[i] = 0.f; c[i] = 0.f; }
}

// ---------------- lengths ----------------
__global__ __launch_bounds__(256) void lens_k(const float* __restrict__ traj,
                                              int* __restrict__ len)
{
    int b = blockIdx.x;
    int cnt = 0;
    for (int i = threadIdx.x; i < TT; i += 256)
        cnt += (traj[b * TT + i] != -1.0f) ? 1 : 0;
    for (int o = 32; o > 0; o >>= 1) cnt += __shfl_down(cnt, o, 64);
    __shared__ int s4[4];
    if ((threadIdx.x & 63) == 0) s4[threadIdx.x >> 6] = cnt;
    __syncthreads();
    if (threadIdx.x == 0) len[b] = s4[0] + s4[1] + s4[2] + s4[3];
}

// ---------------- one LSTM time step ----------------
// grid (32 b-groups, 8 j-groups), block 512.
// wg handles 8 samples x 64 hidden indices (=> 256 gate rows).
// thread: gate = tid>>7, sp = (tid>>4)&7 (sample), jjq = tid&15 (j-quad).
__global__ __launch_bounds__(512) void lstm_step(
    const float* __restrict__ traj, const float* __restrict__ Wih,
    const float* __restrict__ WT, const float* __restrict__ bsum,
    const float* __restrict__ hin, float* __restrict__ hout,
    float* __restrict__ c, int t)
{
    __shared__ float hs[4096];   // [k][s] then reused as gate buffer [j][36]
    __shared__ float xs[8];
    __shared__ float ms[8];

    const int bg = blockIdx.x, jg = blockIdx.y, tid = threadIdx.x;
    const int b0 = bg * 8;
    const int jglob0 = jg * 64;

    if (tid < 8) {
        float v = traj[(b0 + tid) * TT + t];
        xs[tid] = v;
        ms[tid] = (v != -1.0f) ? 1.f : 0.f;
    }
    // stage h: global coalesced read, LDS [k*8+s] layout for broadcast reads
    for (int i = tid; i < 4096; i += 512) {
        int s = i >> 9, k = i & 511;
        hs[k * 8 + s] = hin[(b0 + s) * HH + k];
    }
    __syncthreads();

    bool anyAct = (ms[0] + ms[1] + ms[2] + ms[3] + ms[4] + ms[5] + ms[6] + ms[7]) > 0.f;
    if (!anyAct) {
        // all 8 samples ended: carry h slice forward (double-buffer must be filled)
        int s = tid >> 6, j = tid & 63;
        int hidx = (b0 + s) * HH + jglob0 + j;
        hout[hidx] = hin[hidx];
        return;
    }

    const int gate = tid >> 7;
    const int sp   = (tid >> 4) & 7;
    const int jjq  = tid & 15;
    const int col  = gate * HH + jglob0 + jjq * 4;

    float acc0 = 0.f, acc1 = 0.f, acc2 = 0.f, acc3 = 0.f;
    #pragma unroll 8
    for (int k = 0; k < HH; ++k) {
        float4 w = *(const float4*)&WT[k * G4 + col];
        float hv = hs[k * 8 + sp];
        acc0 += w.x * hv;
        acc1 += w.y * hv;
        acc2 += w.z * hv;
        acc3 += w.w * hv;
    }
    __syncthreads();   // everyone done reading hs; reuse it as gate buffer

    float* gsm = hs;   // [j (64)][36]: j*36 + s*4 + gate  (pad 36 kills bank conflicts)
    float accv[4] = {acc0, acc1, acc2, acc3};
    #pragma unroll
    for (int q = 0; q < 4; ++q) {
        int row = col + q;
        float pre = accv[q] + xs[sp] * Wih[row] + bsum[row];
        float v;
        if (gate == 2) {                       // g: tanh  (wave-uniform branch)
            float e = __expf(2.f * pre);
            v = 1.f - 2.f / (e + 1.f);
        } else {                               // i,f,o: sigmoid
            v = 1.f / (1.f + __expf(-pre));
        }
        gsm[(jjq * 4 + q) * 36 + sp * 4 + gate] = v;
    }
    __syncthreads();

    // update: one (s, j) per thread
    {
        int s = tid >> 6, j = tid & 63;
        int hidx = (b0 + s) * HH + jglob0 + j;
        if (ms[s] > 0.f) {
            float4 g4 = *(const float4*)&gsm[j * 36 + s * 4];
            float iv = g4.x, fv = g4.y, gv = g4.z, ov = g4.w;
            float cn = fv * c[hidx] + iv * gv;
            float e  = __expf(2.f * cn);
            float th = 1.f - 2.f / (e + 1.f);
            c[hidx]    = cn;
            hout[hidx] = ov * th;
        } else {
            hout[hidx] = hin[hidx];
        }
    }
}

// ---------------- epilogue: logits + masked softmax ----------------
__global__ __launch_bounds__(256) void epi_k(
    const float* __restrict__ hfin, const float* __restrict__ fcWT,
    const float* __restrict__ fcb, const int* __restrict__ len,
    float* __restrict__ out)
{
    __shared__ float hb[HH];
    __shared__ float lg[TT];
    __shared__ float red[4];
    const int b = blockIdx.x, tid = threadIdx.x;

    for (int i = tid; i < HH; i += 256) hb[i] = hfin[b * HH + i];
    __syncthreads();

    const int t0 = tid * 4;
    float a0 = fcb[t0], a1 = fcb[t0 + 1], a2 = fcb[t0 + 2], a3 = fcb[t0 + 3];
    #pragma unroll 8
    for (int k = 0; k < HH; ++k) {
        float4 w = *(const float4*)&fcWT[k * TT + t0];
        float hv = hb[k];
        a0 += w.x * hv; a1 += w.y * hv; a2 += w.z * hv; a3 += w.w * hv;
    }
    lg[t0] = a0; lg[t0 + 1] = a1; lg[t0 + 2] = a2; lg[t0 + 3] = a3;
    __syncthreads();

    const int L = len[b];
    float mx = -3.4e38f;
    for (int i = tid; i < L; i += 256) mx = fmaxf(mx, lg[i]);
    for (int o = 32; o > 0; o >>= 1) mx = fmaxf(mx, __shfl_down(mx, o, 64));
    if ((tid & 63) == 0) red[tid >> 6] = mx;
    __syncthreads();
    mx = fmaxf(fmaxf(red[0], red[1]), fmaxf(red[2], red[3]));
    __syncthreads();   // red about to be reused

    float sm = 0.f;
    for (int i = tid; i < L; i += 256) {
        float e = __expf(lg[i] - mx);
        lg[i] = e;
        sm += e;
    }
    for (int o = 32; o > 0; o >>= 1) sm += __shfl_down(sm, o, 64);
    if ((tid & 63) == 0) red[tid >> 6] = sm;
    __syncthreads();
    sm = red[0] + red[1] + red[2] + red[3];
    float inv = 1.f / sm;

    for (int i = tid; i < TT; i += 256)
        out[b * TT + i] = (i < L) ? lg[i] * inv : 1.0f;
}

// ---------------- launch ----------------
extern "C" void kernel_launch(void* const* d_in, const int* in_sizes, int n_in,
                              void* d_out, int out_size, void* d_ws, size_t ws_size,
                              hipStream_t stream)
{
    const float* traj = (const float*)d_in[0];
    const float* Wih  = (const float*)d_in[1];
    const float* Whh  = (const float*)d_in[2];
    const float* bih  = (const float*)d_in[3];
    const float* bhh  = (const float*)d_in[4];
    const float* fcW  = (const float*)d_in[5];
    const float* fcb  = (const float*)d_in[6];
    float* out = (float*)d_out;

    float* ws   = (float*)d_ws;
    float* WT   = ws;                       // 512*2048 = 1048576
    float* fcWT = WT + HH * G4;             // 512*1024 = 524288
    float* bsum = fcWT + HH * TT;           // 2048
    float* h0   = bsum + G4;                // 131072
    float* h1   = h0 + BB * HH;             // 131072
    float* c    = h1 + BB * HH;             // 131072
    int*   len  = (int*)(c + BB * HH);      // 256 ints
    // total ~7.5 MB of d_ws

    prep_k<<<2048, 256, 0, stream>>>(Whh, fcW, bih, bhh, WT, fcWT, bsum, h0, c);
    lens_k<<<BB, 256, 0, stream>>>(traj, len);

    float* hb[2] = {h0, h1};
    for (int t = 0; t < TT; ++t) {
        lstm_step<<<dim3(32, 8), 512, 0, stream>>>(
            traj, Wih, WT, bsum, hb[t & 1], hb[(t + 1) & 1], c, t);
    }
    // final h is in hb[TT & 1] == h0
    epi_k<<<BB, 256, 0, stream>>>(h0, fcWT, fcb, len, out);
}